// Round 12
// baseline (7323.289 us; speedup 1.0000x reference)
//
#include <hip/hip_runtime.h>

// Echo State Network, T=1024 sequential steps of r' = 0.5 r + 0.5 tanh(W r + Win u).
// Persistent kernel. W pinned in hard-named AGPRs (verified r4: VGPR_Count=128).
//
// r12 = r6's MERGED notification+payload (self-tagged 8B units), fixed:
//  * r6's failure was SERIAL per-unit retries (8 x 0.7us L3 latency worst case,
//    divergent reloads -> 465 MB FETCH, 8 ms). Fix: BATCHED rounds — issue all
//    8 tagged loads MLP'd, recheck, re-issue ALL on any stale; each round costs
//    one L3 latency. Coalesced tid+512j mapping kept (conflict-free LDS too).
//  * No flags, no barrier B, no vmcnt drain, no memset node. Tags self-certify:
//    consumer sees tag==t => producer's value is there. Ping-pong safe (r6
//    argument): passing step-t check + barrier A proves all WGs consumed
//    r(t-1). Replay-safe: stale final tags (1023/1024) can't match expectation
//    before ~511 in-run overwrites of that slot; poison/zero never match 1..1024.
//  * Rotated pred (r11) in the post-publish shadow; barrier C before the LDS
//    writes protects pred's r_lds reads from next-step staging (intra-WG only).
//
// RACE DETECTOR: absmax must read exactly 6.103516e-05. Anything else => race.
//
// d_ws layout: [0, 65536): ull rbuf2[2][4096]  (tagged, double-buffered r)

#define T_STEPS 1024
#define R_DIM   4096
#define N_WG    256
#define N_THR   512
#define ROWS_PER_WG 16
#define K_CHUNKS 16          // R_DIM / (64 lanes * 4 floats)

#define AGENT __HIP_MEMORY_SCOPE_AGENT

typedef unsigned long long ull;
typedef unsigned int uint32;

__device__ __forceinline__ float fast_tanh(float x) {
    float ax = fabsf(x);
    float e  = __expf(-2.0f * ax);
    float t  = (1.0f - e) / (1.0f + e);
    return copysignf(t, x);
}

// Store one float4 into four named physical AGPRs.
#define WST4(A0, A1, A2, A3, vec)                                              \
    asm volatile("v_accvgpr_write_b32 a" #A0 ", %0\n\t"                        \
                 "v_accvgpr_write_b32 a" #A1 ", %1\n\t"                        \
                 "v_accvgpr_write_b32 a" #A2 ", %2\n\t"                        \
                 "v_accvgpr_write_b32 a" #A3 ", %3"                            \
                 :: "v"((vec).x), "v"((vec).y), "v"((vec).z), "v"((vec).w)     \
                 : "a" #A0, "a" #A1, "a" #A2, "a" #A3)

// One K-chunk of the two-row matvec: read 4+4 W values from AGPRs, FMA with rv.
#define MV2(c, A0, A1, A2, A3, B0, B1, B2, B3)                                 \
    do {                                                                       \
        float4 rv = rv4[(c) * 64 + lane];                                      \
        float w0, w1, w2, w3, u0, u1, u2, u3;                                  \
        asm volatile("v_accvgpr_read_b32 %0, a" #A0 "\n\t"                     \
                     "v_accvgpr_read_b32 %1, a" #A1 "\n\t"                     \
                     "v_accvgpr_read_b32 %2, a" #A2 "\n\t"                     \
                     "v_accvgpr_read_b32 %3, a" #A3 "\n\t"                     \
                     "v_accvgpr_read_b32 %4, a" #B0 "\n\t"                     \
                     "v_accvgpr_read_b32 %5, a" #B1 "\n\t"                     \
                     "v_accvgpr_read_b32 %6, a" #B2 "\n\t"                     \
                     "v_accvgpr_read_b32 %7, a" #B3                            \
                     : "=v"(w0), "=v"(w1), "=v"(w2), "=v"(w3),                 \
                       "=v"(u0), "=v"(u1), "=v"(u2), "=v"(u3));                \
        accA.x = fmaf(w0, rv.x, accA.x);                                       \
        accA.y = fmaf(w1, rv.y, accA.y);                                       \
        accA.z = fmaf(w2, rv.z, accA.z);                                       \
        accA.w = fmaf(w3, rv.w, accA.w);                                       \
        accB.x = fmaf(u0, rv.x, accB.x);                                       \
        accB.y = fmaf(u1, rv.y, accB.y);                                       \
        accB.z = fmaf(u2, rv.z, accB.z);                                       \
        accB.w = fmaf(u3, rv.w, accB.w);                                       \
    } while (0)

#define LD8(k) __hip_atomic_load(src + tid + (k) * 512, __ATOMIC_RELAXED, AGENT)

__global__ __launch_bounds__(N_THR, 2)
void esn_persistent(const float* __restrict__ batch,
                    const float* __restrict__ Win,
                    const float* __restrict__ W,
                    const float* __restrict__ Wout,
                    float* __restrict__ out,
                    ull*   __restrict__ rbuf2)
{
    __shared__ __align__(16) float r_lds[R_DIM];   // current r(t)
    __shared__ float b_lds[T_STEPS];               // input sequence

    const int tid  = threadIdx.x;
    const int wid  = blockIdx.x;
    const int wave = tid >> 6;
    const int lane = tid & 63;
    const int rowA = wid * ROWS_PER_WG + wave * 2; // this wave's two W rows
    const int rowB = rowA + 1;

    for (int i = tid; i < R_DIM; i += N_THR) r_lds[i] = 0.0f;   // r(0) = 0
    for (int i = tid; i < T_STEPS; i += N_THR) b_lds[i] = batch[i];

    // Pin W rows in physical AGPRs. Lane's chunk c covers k = c*256 + lane*4.
    {
        const float4* pA = reinterpret_cast<const float4*>(W + (size_t)rowA * R_DIM);
        const float4* pB = reinterpret_cast<const float4*>(W + (size_t)rowB * R_DIM);
        float4 v;
        v = pA[ 0 * 64 + lane]; WST4(  0,   1,   2,   3, v);
        v = pA[ 1 * 64 + lane]; WST4(  4,   5,   6,   7, v);
        v = pA[ 2 * 64 + lane]; WST4(  8,   9,  10,  11, v);
        v = pA[ 3 * 64 + lane]; WST4( 12,  13,  14,  15, v);
        v = pA[ 4 * 64 + lane]; WST4( 16,  17,  18,  19, v);
        v = pA[ 5 * 64 + lane]; WST4( 20,  21,  22,  23, v);
        v = pA[ 6 * 64 + lane]; WST4( 24,  25,  26,  27, v);
        v = pA[ 7 * 64 + lane]; WST4( 28,  29,  30,  31, v);
        v = pA[ 8 * 64 + lane]; WST4( 32,  33,  34,  35, v);
        v = pA[ 9 * 64 + lane]; WST4( 36,  37,  38,  39, v);
        v = pA[10 * 64 + lane]; WST4( 40,  41,  42,  43, v);
        v = pA[11 * 64 + lane]; WST4( 44,  45,  46,  47, v);
        v = pA[12 * 64 + lane]; WST4( 48,  49,  50,  51, v);
        v = pA[13 * 64 + lane]; WST4( 52,  53,  54,  55, v);
        v = pA[14 * 64 + lane]; WST4( 56,  57,  58,  59, v);
        v = pA[15 * 64 + lane]; WST4( 60,  61,  62,  63, v);
        v = pB[ 0 * 64 + lane]; WST4( 64,  65,  66,  67, v);
        v = pB[ 1 * 64 + lane]; WST4( 68,  69,  70,  71, v);
        v = pB[ 2 * 64 + lane]; WST4( 72,  73,  74,  75, v);
        v = pB[ 3 * 64 + lane]; WST4( 76,  77,  78,  79, v);
        v = pB[ 4 * 64 + lane]; WST4( 80,  81,  82,  83, v);
        v = pB[ 5 * 64 + lane]; WST4( 84,  85,  86,  87, v);
        v = pB[ 6 * 64 + lane]; WST4( 88,  89,  90,  91, v);
        v = pB[ 7 * 64 + lane]; WST4( 92,  93,  94,  95, v);
        v = pB[ 8 * 64 + lane]; WST4( 96,  97,  98,  99, v);
        v = pB[ 9 * 64 + lane]; WST4(100, 101, 102, 103, v);
        v = pB[10 * 64 + lane]; WST4(104, 105, 106, 107, v);
        v = pB[11 * 64 + lane]; WST4(108, 109, 110, 111, v);
        v = pB[12 * 64 + lane]; WST4(112, 113, 114, 115, v);
        v = pB[13 * 64 + lane]; WST4(116, 117, 118, 119, v);
        v = pB[14 * 64 + lane]; WST4(120, 121, 122, 123, v);
        v = pB[15 * 64 + lane]; WST4(124, 125, 126, 127, v);
    }
    const float winA0 = Win[2 * rowA], winA1 = Win[2 * rowA + 1];
    const float winB0 = Win[2 * rowB], winB1 = Win[2 * rowB + 1];

    __syncthreads();

    const float4* rv4 = reinterpret_cast<const float4*>(r_lds);

    for (int t = 0; t < T_STEPS; ++t) {
        if (t > 0) {
            // Merged detect+fetch: 8 tagged units/thread, coalesced tid+512j.
            // BATCHED rounds: all 8 loads in flight, check, re-issue ALL if any
            // stale — each round costs ONE L3 latency, not eight.
            const ull* src = rbuf2 + (size_t)(t & 1) * R_DIM;
            const uint32 texp = (uint32)t;
            ull v0 = LD8(0), v1 = LD8(1), v2 = LD8(2), v3 = LD8(3),
                v4 = LD8(4), v5 = LD8(5), v6 = LD8(6), v7 = LD8(7);
            for (;;) {
                bool ok = ((uint32)(v0 >> 32) == texp) & ((uint32)(v1 >> 32) == texp)
                        & ((uint32)(v2 >> 32) == texp) & ((uint32)(v3 >> 32) == texp)
                        & ((uint32)(v4 >> 32) == texp) & ((uint32)(v5 >> 32) == texp)
                        & ((uint32)(v6 >> 32) == texp) & ((uint32)(v7 >> 32) == texp);
                if (ok) break;
                __builtin_amdgcn_s_sleep(1);
                v0 = LD8(0); v1 = LD8(1); v2 = LD8(2); v3 = LD8(3);
                v4 = LD8(4); v5 = LD8(5); v6 = LD8(6); v7 = LD8(7);
            }
            __syncthreads();   // barrier C: prior-step pred's r_lds reads done
            r_lds[tid + 0 * 512] = __uint_as_float((uint32)v0);
            r_lds[tid + 1 * 512] = __uint_as_float((uint32)v1);
            r_lds[tid + 2 * 512] = __uint_as_float((uint32)v2);
            r_lds[tid + 3 * 512] = __uint_as_float((uint32)v3);
            r_lds[tid + 4 * 512] = __uint_as_float((uint32)v4);
            r_lds[tid + 5 * 512] = __uint_as_float((uint32)v5);
            r_lds[tid + 6 * 512] = __uint_as_float((uint32)v6);
            r_lds[tid + 7 * 512] = __uint_as_float((uint32)v7);
            __syncthreads();   // barrier A: r(t) staged (and: whole WG saw all tags==t)
        }

        // y = W r(t) for this wave's two rows (W in AGPRs, r broadcast from LDS).
        float4 accA = make_float4(0.f, 0.f, 0.f, 0.f);
        float4 accB = make_float4(0.f, 0.f, 0.f, 0.f);
        MV2( 0,   0,   1,   2,   3,  64,  65,  66,  67);
        MV2( 1,   4,   5,   6,   7,  68,  69,  70,  71);
        MV2( 2,   8,   9,  10,  11,  72,  73,  74,  75);
        MV2( 3,  12,  13,  14,  15,  76,  77,  78,  79);
        MV2( 4,  16,  17,  18,  19,  80,  81,  82,  83);
        MV2( 5,  20,  21,  22,  23,  84,  85,  86,  87);
        MV2( 6,  24,  25,  26,  27,  88,  89,  90,  91);
        MV2( 7,  28,  29,  30,  31,  92,  93,  94,  95);
        MV2( 8,  32,  33,  34,  35,  96,  97,  98,  99);
        MV2( 9,  36,  37,  38,  39, 100, 101, 102, 103);
        MV2(10,  40,  41,  42,  43, 104, 105, 106, 107);
        MV2(11,  44,  45,  46,  47, 108, 109, 110, 111);
        MV2(12,  48,  49,  50,  51, 112, 113, 114, 115);
        MV2(13,  52,  53,  54,  55, 116, 117, 118, 119);
        MV2(14,  56,  57,  58,  59, 120, 121, 122, 123);
        MV2(15,  60,  61,  62,  63, 124, 125, 126, 127);

        float sA = (accA.x + accA.y) + (accA.z + accA.w);
        float sB = (accB.x + accB.y) + (accB.z + accB.w);
        #pragma unroll
        for (int m = 1; m < 64; m <<= 1) {
            sA += __shfl_xor(sA, m);
            sB += __shfl_xor(sB, m);
        }

        // Per-wave publish: two tagged 8B atoms, tag = t+1. No drain, no flag.
        // Ping-pong safe: this WG passed barrier A for step t (all tags==t seen
        // by the whole WG), so every WG has finished reading r(t-1) from the
        // destination buffer.
        if (lane == 0) {
            float bt = b_lds[t];
            float xA = fast_tanh(sA + fmaf(winA1, bt, winA0));
            float xB = fast_tanh(sB + fmaf(winB1, bt, winB0));
            float rnA = 0.5f * (r_lds[rowA] + xA);
            float rnB = 0.5f * (r_lds[rowB] + xB);
            ull tagw = (ull)(uint32)(t + 1) << 32;
            ull* dst = rbuf2 + (size_t)((t + 1) & 1) * R_DIM;
            __hip_atomic_store(dst + rowA, tagw | __float_as_uint(rnA),
                               __ATOMIC_RELAXED, AGENT);
            __hip_atomic_store(dst + rowB, tagw | __float_as_uint(rnB),
                               __ATOMIC_RELAXED, AGENT);
        }

        // Rotated pred in the publish shadow: WG ((t-1)&255) wave0 computes
        // out[t-1] from r_lds = r(t). Next-step staging LDS writes are gated
        // by barrier C, which this wave reaches only after finishing pred.
        if (t >= 1 && wave == 0 && wid == ((t - 1) & 255)) {
            const float* wr = Wout + 2;
            float s = 0.0f;
            #pragma unroll
            for (int c = 0; c < K_CHUNKS; ++c) {
                int k = c * 256 + lane * 4;
                float2 wa = *reinterpret_cast<const float2*>(wr + k);
                float2 wb = *reinterpret_cast<const float2*>(wr + k + 2);
                float4 rv = rv4[c * 64 + lane];
                s = fmaf(wa.x, rv.x, s);
                s = fmaf(wa.y, rv.y, s);
                s = fmaf(wb.x, rv.z, s);
                s = fmaf(wb.y, rv.w, s);
            }
            #pragma unroll
            for (int m = 1; m < 64; m <<= 1) s += __shfl_xor(s, m);
            if (lane == 0)
                out[t - 1] = s + fmaf(Wout[1], b_lds[t - 1], Wout[0]);
        }
    }

    // Epilogue (WG0 only): out[T-1] from r(T) (tags == T_STEPS in buf[0]).
    if (wid == 0) {
        const ull* src = rbuf2 + (size_t)(T_STEPS & 1) * R_DIM;
        const uint32 texp = (uint32)T_STEPS;
        ull v0 = LD8(0), v1 = LD8(1), v2 = LD8(2), v3 = LD8(3),
            v4 = LD8(4), v5 = LD8(5), v6 = LD8(6), v7 = LD8(7);
        for (;;) {
            bool ok = ((uint32)(v0 >> 32) == texp) & ((uint32)(v1 >> 32) == texp)
                    & ((uint32)(v2 >> 32) == texp) & ((uint32)(v3 >> 32) == texp)
                    & ((uint32)(v4 >> 32) == texp) & ((uint32)(v5 >> 32) == texp)
                    & ((uint32)(v6 >> 32) == texp) & ((uint32)(v7 >> 32) == texp);
            if (ok) break;
            __builtin_amdgcn_s_sleep(1);
            v0 = LD8(0); v1 = LD8(1); v2 = LD8(2); v3 = LD8(3);
            v4 = LD8(4); v5 = LD8(5); v6 = LD8(6); v7 = LD8(7);
        }
        __syncthreads();   // last rotated pred in this WG (if any) done
        r_lds[tid + 0 * 512] = __uint_as_float((uint32)v0);
        r_lds[tid + 1 * 512] = __uint_as_float((uint32)v1);
        r_lds[tid + 2 * 512] = __uint_as_float((uint32)v2);
        r_lds[tid + 3 * 512] = __uint_as_float((uint32)v3);
        r_lds[tid + 4 * 512] = __uint_as_float((uint32)v4);
        r_lds[tid + 5 * 512] = __uint_as_float((uint32)v5);
        r_lds[tid + 6 * 512] = __uint_as_float((uint32)v6);
        r_lds[tid + 7 * 512] = __uint_as_float((uint32)v7);
        __syncthreads();
        if (wave == 0) {
            const float* wr = Wout + 2;
            float s = 0.0f;
            #pragma unroll
            for (int c = 0; c < K_CHUNKS; ++c) {
                int k = c * 256 + lane * 4;
                float2 wa = *reinterpret_cast<const float2*>(wr + k);
                float2 wb = *reinterpret_cast<const float2*>(wr + k + 2);
                float4 rv = rv4[c * 64 + lane];
                s = fmaf(wa.x, rv.x, s);
                s = fmaf(wa.y, rv.y, s);
                s = fmaf(wb.x, rv.z, s);
                s = fmaf(wb.y, rv.w, s);
            }
            #pragma unroll
            for (int m = 1; m < 64; m <<= 1) s += __shfl_xor(s, m);
            if (lane == 0)
                out[T_STEPS - 1] = s + fmaf(Wout[1], b_lds[T_STEPS - 1], Wout[0]);
        }
    }
}

extern "C" void kernel_launch(void* const* d_in, const int* in_sizes, int n_in,
                              void* d_out, int out_size, void* d_ws, size_t ws_size,
                              hipStream_t stream) {
    (void)in_sizes; (void)n_in; (void)out_size; (void)ws_size;
    const float* batch = (const float*)d_in[0];   // (1024,1,1)
    const float* Win   = (const float*)d_in[1];   // (4096,2) row-major
    const float* W     = (const float*)d_in[2];   // (4096,4096) row-major
    const float* Wout  = (const float*)d_in[3];   // (1,4098)
    float* out  = (float*)d_out;                  // (1024,1)
    ull*   rbuf2 = (ull*)d_ws;                    // 2*4096 tagged units (64 KB)

    // No init node: tag check is exact-match. Poison 0xAAAAAAAA / zeros never
    // equal tags 1..1024; stale FINAL tags (1023/1024) from a previous replay
    // sit in slots that get overwritten ~511 times before those tags are
    // expected again. (r6 ran this scheme absmax-clean across all replays.)

    // grid=256 WGs x 512 thr (8 waves = 2 waves/SIMD; 128 AGPR + ~110 VGPR
    // fits 2/SIMD). grid == CU count => all WGs co-resident for the tag spin.
    esn_persistent<<<dim3(N_WG), dim3(N_THR), 0, stream>>>(
        batch, Win, W, Wout, out, rbuf2);
}